// Round 7
// baseline (502.745 us; speedup 1.0000x reference)
//
#include <hip/hip_runtime.h>
#include <hip/hip_cooperative_groups.h>
#include <stdint.h>

namespace cg = cooperative_groups;

#define BATCH 8192
#define NVB   1024   // virtual blocks per heavy phase, 8 images each

// ws byte offsets
#define OFF_W1R3  0          // uint32[96]   w1 signs, 3 rows x 9 bits per word
#define OFF_W2P   384        // uint32[1440] w2 signs [och 8][kh 9][kw 10 pad] x uint2
#define OFF_W3P   6144       // uint32[864]  w3 signs [oc 8][kh 9][kw 12 pad]
#define OFF_WLB   9600       // uint64[20]   wl signs, 128 bits per oc
#define OFF_SBL   9760       // float[10]    sign(bl)
#define OFF_TPART 9856       // int[1024][81]  layer-1 window-sum partials
#define OFF_S2P   341632     // int[1024][16]  layer-2 channel-sum partials (per real block)
#define OFF_S3P   407168     // int[1024][8]   layer-3 channel-sum partials (per real block)
#define OFF_Z2    440320     // uint32[8192][1152] : int16 z2 [img][px 144][oc 16]
#define OFF_Z3    38189056   // uint32[8192][64]   : int16 z3 [img][oc 8][px 16]
// total 40286208 bytes (~40.3 MB)

struct PhaseA { uint32_t rowm[224]; int Tacc[81]; };
struct PhaseB { uint32_t rowm[224]; uint32_t w1r3[96]; uint32_t w2p[1440];
                int red[256]; int tlds[81]; int t1s[32];
                uint32_t A1s[3200]; int s2acc[16]; };
struct PhaseC { uint32_t w3p[864]; int part[256]; int t2s[16]; int s3acc[8];
                uint32_t A2[1152]; };
struct PhaseD { int red[128]; int t3[8]; uint64_t wlb[20]; float sbl[10]; };
union SMemU { PhaseA a; PhaseB b; PhaseC c; PhaseD d; };

__global__ __launch_bounds__(256)
void fused_bnn(const float* __restrict__ x,  const float* __restrict__ w1,
               const float* __restrict__ w2, const float* __restrict__ w3,
               const float* __restrict__ wl, const float* __restrict__ bl,
               uint8_t* __restrict__ ws, float* __restrict__ out) {
  cg::grid_group grid = cg::this_grid();
  __shared__ __align__(16) SMemU sm;
  const int tid = threadIdx.x;
  const int G = gridDim.x;

  int* TPART = (int*)(ws + OFF_TPART);
  int* S2P   = (int*)(ws + OFF_S2P);
  int* S3P   = (int*)(ws + OFF_S3P);
  uint32_t* Z2w = (uint32_t*)(ws + OFF_Z2);
  uint32_t* Z3w = (uint32_t*)(ws + OFF_Z3);

  // ================= Phase A: weight packing (blocks 0..3) + window sums =================
  if (blockIdx.x == 0) {           // w2: (16,32,9,9) -> [och][kh][kw pad10] uint2 over ic
    uint32_t* W2P = (uint32_t*)(ws + OFF_W2P);
    for (int e = tid; e < 648; e += 256) {
      int och = e / 81, k = e % 81, kh = k / 9, kw = k % 9;
      uint32_t m0 = 0, m1 = 0;
      int oc0 = och * 2;
      for (int ic = 0; ic < 32; ++ic) {
        if (w2[(oc0*32 + ic)*81 + k] < 0.f)     m0 |= 1u << ic;
        if (w2[((oc0+1)*32 + ic)*81 + k] < 0.f) m1 |= 1u << ic;
      }
      int idx = ((och*9 + kh)*10 + kw)*2;
      W2P[idx] = m0; W2P[idx+1] = m1;
    }
    for (int e = tid; e < 72; e += 256) { int idx = (e*10 + 9)*2; W2P[idx] = 0; W2P[idx+1] = 0; }
  } else if (blockIdx.x == 1) {    // w3: (8,16,9,9) -> [oc][kh][kw pad12]
    uint32_t* W3P = (uint32_t*)(ws + OFF_W3P);
    for (int e = tid; e < 648; e += 256) {
      int oc = e / 81, k = e % 81, kh = k / 9, kw = k % 9;
      uint32_t m = 0;
      for (int ic = 0; ic < 16; ++ic)
        if (w3[(oc*16 + ic)*81 + k] < 0.f) m |= 1u << ic;
      W3P[(oc*9 + kh)*12 + kw] = m;
    }
    for (int e = tid; e < 216; e += 256) { int row = e / 3, p = e % 3; W3P[row*12 + 9 + p] = 0; }
  } else if (blockIdx.x == 2) {    // w1: (32,1,9,9) -> 3 rows x 9 bits per word
    uint32_t* W1R3 = (uint32_t*)(ws + OFF_W1R3);
    for (int e = tid; e < 96; e += 256) {
      int oc = e / 3, i = e % 3;
      uint32_t m = 0;
      for (int rr = 0; rr < 3; ++rr)
        for (int kw = 0; kw < 9; ++kw)
          if (w1[oc*81 + (3*i+rr)*9 + kw] < 0.f) m |= 1u << (rr*9 + kw);
      W1R3[e] = m;
    }
  } else if (blockIdx.x == 3) {    // wl bits + sign(bl)
    uint64_t* WLB = (uint64_t*)(ws + OFF_WLB);
    float* SBL = (float*)(ws + OFF_SBL);
    for (int e = tid; e < 20; e += 256) {
      int oc = e >> 1, word = e & 1;
      uint64_t m = 0;
      for (int b = 0; b < 64; ++b)
        if (wl[oc*128 + word*64 + b] < 0.f) m |= 1ull << b;
      WLB[e] = m;
    }
    if (tid < 10) SBL[tid] = (bl[tid] >= 0.f) ? 1.f : -1.f;
  }

  for (int vb = blockIdx.x; vb < NVB; vb += G) {
    if (tid < 81) sm.a.Tacc[tid] = 0;
    __syncthreads();
    const int img0 = vb * 8;
    if (tid < 224) {
      int il = tid / 28, r = tid % 28;
      const float4* xr = (const float4*)(x + (size_t)(img0 + il) * 784 + r * 28);
      uint32_t m = 0;
      #pragma unroll
      for (int j = 0; j < 7; ++j) {
        float4 v = xr[j];
        if (v.x < 0.f) m |= 1u << (j*4+0);
        if (v.y < 0.f) m |= 1u << (j*4+1);
        if (v.z < 0.f) m |= 1u << (j*4+2);
        if (v.w < 0.f) m |= 1u << (j*4+3);
      }
      sm.a.rowm[tid] = m;
    }
    __syncthreads();
    if (tid < 72) {                // (il, kw): sliding 20-row window of neg counts
      int il = tid / 9, kw = tid % 9;
      int base = il * 28;
      int n9[9];
      int sum20 = 0;
      #pragma unroll
      for (int r = 0; r < 20; ++r) {
        int n = __popc((sm.a.rowm[base + r] >> kw) & 0xFFFFFu);
        if (r < 9) n9[r] = n;
        sum20 += n;
      }
      atomicAdd(&sm.a.Tacc[kw], 400 - 2*sum20);
      #pragma unroll
      for (int kh = 1; kh <= 8; ++kh) {
        int nadd = __popc((sm.a.rowm[base + kh + 19] >> kw) & 0xFFFFFu);
        sum20 += nadd - n9[kh-1];
        atomicAdd(&sm.a.Tacc[kh*9 + kw], 400 - 2*sum20);
      }
    }
    __syncthreads();
    if (tid < 81) TPART[vb*81 + tid] = sm.a.Tacc[tid];
    __syncthreads();
  }
  __threadfence();
  grid.sync();

  // ================= Phase B: conv1 (recompute) + conv2 =================
  {
    const uint32_t* W1R3g = (const uint32_t*)(ws + OFF_W1R3);
    const uint32_t* W2Pg  = (const uint32_t*)(ws + OFF_W2P);
    for (int e = tid; e < 96; e += 256)   sm.b.w1r3[e] = W1R3g[e];
    for (int e = tid; e < 1440; e += 256) sm.b.w2p[e]  = W2Pg[e];
    // Ttot reduction: TPART[1024][81] -> tlds[81] (3 sub-partials per k, coalesced)
    {
      int s = 0;
      if (tid < 243) {
        int k = tid % 81, sub = tid / 81;
        for (int r = sub; r < NVB; r += 3) s += TPART[r*81 + k];
      }
      sm.b.red[tid] = s;
    }
    __syncthreads();
    if (tid < 81) sm.b.tlds[tid] = sm.b.red[tid] + sm.b.red[tid+81] + sm.b.red[tid+162];
    __syncthreads();
    // layer-1 thresholds (odd parity): t1 = smallest odd integer >= S1/N1
    if (tid < 32) {
      long long S = 0;
      for (int kh = 0; kh < 9; ++kh)
        for (int kw = 0; kw < 9; ++kw) {
          int bit = (sm.b.w1r3[tid*3 + kh/3] >> ((kh%3)*9 + kw)) & 1;
          S += (long long)(1 - 2*bit) * sm.b.tlds[kh*9 + kw];
        }
      const long long N1 = (long long)BATCH * 400;
      long long q = S / N1, rr = S % N1;
      long long t = q + (rr > 0 ? 1 : 0);
      if ((t & 1) == 0) t += 1;
      sm.b.t1s[tid] = (int)t;
    }
    if (tid < 16) sm.b.s2acc[tid] = 0;
    __syncthreads();

    const int och = tid & 7, oc0 = och << 1;
    for (int vb = blockIdx.x; vb < NVB; vb += G) {
      const int img0 = vb * 8;
      if (tid < 224) {
        int il = tid / 28, rr = tid % 28;
        const float4* xr = (const float4*)(x + (size_t)(img0 + il) * 784 + rr * 28);
        uint32_t m = 0;
        #pragma unroll
        for (int j = 0; j < 7; ++j) {
          float4 v = xr[j];
          if (v.x < 0.f) m |= 1u << (j*4+0);
          if (v.y < 0.f) m |= 1u << (j*4+1);
          if (v.z < 0.f) m |= 1u << (j*4+2);
          if (v.w < 0.f) m |= 1u << (j*4+3);
        }
        sm.b.rowm[tid] = m;
      }
      __syncthreads();

      // conv1 + binarize -> A1s. Task = (il, oh, 5-ow group): 640 tasks.
      for (int Gt = tid; Gt < 640; Gt += 256) {
        int il = Gt / 80, rem = Gt - il*80;
        int oh = rem >> 2, ow0 = (rem & 3) * 5;
        uint32_t R[9];
        #pragma unroll
        for (int i = 0; i < 9; ++i) R[i] = sm.b.rowm[il*28 + oh + i];
        uint32_t win[5][3];
        #pragma unroll
        for (int j = 0; j < 5; ++j) {
          int ow = ow0 + j;
          #pragma unroll
          for (int i = 0; i < 3; ++i) {
            uint32_t b0 = (R[3*i]   >> ow) & 0x1FFu;
            uint32_t b1 = (R[3*i+1] >> ow) & 0x1FFu;
            uint32_t b2 = (R[3*i+2] >> ow) & 0x1FFu;
            win[j][i] = b0 | (b1 << 9) | (b2 << 18);
          }
        }
        uint32_t mask[5] = {0,0,0,0,0};
        #pragma unroll
        for (int ocg = 0; ocg < 4; ++ocg) {
          const uint4* wp = (const uint4*)&sm.b.w1r3[ocg*24];
          uint32_t wr[24];
          #pragma unroll
          for (int q = 0; q < 6; ++q) {
            uint4 v = wp[q];
            wr[q*4+0]=v.x; wr[q*4+1]=v.y; wr[q*4+2]=v.z; wr[q*4+3]=v.w;
          }
          #pragma unroll
          for (int o8 = 0; o8 < 8; ++o8) {
            int oc = ocg*8 + o8;
            int t = sm.b.t1s[oc];
            #pragma unroll
            for (int j = 0; j < 5; ++j) {
              int mm = __popc(win[j][0] ^ wr[o8*3])
                     + __popc(win[j][1] ^ wr[o8*3+1])
                     + __popc(win[j][2] ^ wr[o8*3+2]);
              mask[j] |= (uint32_t)((81 - 2*mm) < t) << oc;
            }
          }
        }
        #pragma unroll
        for (int j = 0; j < 5; ++j) sm.b.A1s[il*400 + oh*20 + ow0 + j] = mask[j];
      }
      __syncthreads();

      // conv2: task = (il, oy, oc-pair): 768 tasks, 3 per thread.
      int sl0 = 0, sl1 = 0;
      for (int r = 0; r < 3; ++r) {
        int Gt = tid + r*256;
        int il = Gt / 96, rem = Gt - il*96;
        int oy = rem >> 3;
        const uint32_t* A = &sm.b.A1s[il*400 + oy*20];
        int acc0[12], acc1[12];
        #pragma unroll
        for (int p = 0; p < 12; ++p) { acc0[p] = 0; acc1[p] = 0; }
        for (int kh = 0; kh < 9; ++kh) {
          const uint4* ar = (const uint4*)(A + kh*20);
          uint32_t a[20];
          #pragma unroll
          for (int q = 0; q < 5; ++q) {
            uint4 v = ar[q];
            a[q*4+0]=v.x; a[q*4+1]=v.y; a[q*4+2]=v.z; a[q*4+3]=v.w;
          }
          const uint4* wp4 = (const uint4*)&sm.b.w2p[(och*9 + kh)*20];
          uint32_t wbuf[20];
          #pragma unroll
          for (int q = 0; q < 5; ++q) {
            uint4 v = wp4[q];
            wbuf[q*4+0]=v.x; wbuf[q*4+1]=v.y; wbuf[q*4+2]=v.z; wbuf[q*4+3]=v.w;
          }
          #pragma unroll
          for (int kw = 0; kw < 9; ++kw) {
            uint32_t w0 = wbuf[2*kw], w1v = wbuf[2*kw+1];
            #pragma unroll
            for (int px = 0; px < 12; ++px) {
              acc0[px] += __popc(a[kw+px] ^ w0);
              acc1[px] += __popc(a[kw+px] ^ w1v);
            }
          }
        }
        size_t wbase = (size_t)(img0+il)*1152 + (size_t)oy*96 + och;
        #pragma unroll
        for (int px = 0; px < 12; ++px) {
          int z0 = 2592 - 2*acc0[px], z1v = 2592 - 2*acc1[px];
          sl0 += z0; sl1 += z1v;
          Z2w[wbase + px*8] = (uint32_t)(uint16_t)(int16_t)z0
                            | ((uint32_t)(uint16_t)(int16_t)z1v << 16);
        }
      }
      atomicAdd(&sm.b.s2acc[oc0],   sl0);
      atomicAdd(&sm.b.s2acc[oc0+1], sl1);
      __syncthreads();
    }
    if (tid < 16) S2P[blockIdx.x*16 + tid] = sm.b.s2acc[tid];
  }
  __threadfence();
  grid.sync();

  // ================= Phase C: t2 reduce + binarize + conv3 =================
  {
    const uint32_t* W3Pg = (const uint32_t*)(ws + OFF_W3P);
    {
      int c = tid & 15, g = tid >> 4;
      int s = 0;
      for (int b = g; b < G; b += 16) s += S2P[b*16 + c];
      sm.c.part[tid] = s;
    }
    for (int e = tid; e < 864; e += 256) sm.c.w3p[e] = W3Pg[e];
    if (tid < 8) sm.c.s3acc[tid] = 0;
    __syncthreads();
    if (tid < 16) {
      long long S = 0;
      #pragma unroll
      for (int g = 0; g < 16; ++g) S += (long long)sm.c.part[g*16 + tid];
      const long long N2 = (long long)BATCH * 144;
      long long q = S / N2, r = S % N2;
      long long t = q + (r > 0 ? 1 : 0);
      if (t & 1) t += 1;   // z2 is even
      sm.c.t2s[tid] = (int)t;
    }
    __syncthreads();

    for (int vb = blockIdx.x; vb < NVB; vb += G) {
      const int img0 = vb * 8;
      // binarize z2 -> A2 masks. 8 imgs x 144 px, coalesced 32B/px.
      for (int idx = tid; idx < 1152; idx += 256) {
        const uint4* zp = (const uint4*)&Z2w[(size_t)(img0 + idx/144)*1152 + (size_t)(idx%144)*8];
        uint4 v0 = zp[0], v1 = zp[1];
        uint32_t zz[8] = {v0.x,v0.y,v0.z,v0.w, v1.x,v1.y,v1.z,v1.w};
        uint32_t m = 0;
        #pragma unroll
        for (int i = 0; i < 8; ++i) {
          int zlo = (int)(short)(zz[i] & 0xFFFFu);
          int zhi = (int)zz[i] >> 16;
          m |= (uint32_t)(zlo < sm.c.t2s[2*i])   << (2*i);
          m |= (uint32_t)(zhi < sm.c.t2s[2*i+1]) << (2*i+1);
        }
        sm.c.A2[idx] = m;
      }
      __syncthreads();
      // conv3: task = (il, oc, oy): tid = il*32 + oc*4 + oy, 4 px per thread.
      {
        const int il = tid >> 5, oc = (tid >> 2) & 7, oy = tid & 3;
        int acc[4] = {0, 0, 0, 0};
        #pragma unroll
        for (int kh = 0; kh < 9; ++kh) {
          const uint4* ar = (const uint4*)&sm.c.A2[il*144 + (oy + kh)*12];
          uint4 v0 = ar[0], v1 = ar[1], v2 = ar[2];
          uint32_t a[12] = {v0.x,v0.y,v0.z,v0.w, v1.x,v1.y,v1.z,v1.w, v2.x,v2.y,v2.z,v2.w};
          const uint4* wr = (const uint4*)&sm.c.w3p[(oc*9 + kh)*12];
          uint4 w0 = wr[0], w1v = wr[1], w2v = wr[2];
          uint32_t w[9] = {w0.x,w0.y,w0.z,w0.w, w1v.x,w1v.y,w1v.z,w1v.w, w2v.x};
          #pragma unroll
          for (int ox = 0; ox < 4; ++ox) {
            #pragma unroll
            for (int kw = 0; kw < 9; ++kw) acc[ox] += __popc(a[ox+kw] ^ w[kw]);
          }
        }
        int ssum = 0;
        uint32_t packed[2];
        #pragma unroll
        for (int h = 0; h < 2; ++h) {
          int za = 1296 - 2*acc[2*h], zb = 1296 - 2*acc[2*h+1];
          ssum += za + zb;
          packed[h] = (uint32_t)(uint16_t)(int16_t)za | ((uint32_t)(uint16_t)(int16_t)zb << 16);
        }
        *(uint2*)&Z3w[(size_t)(img0 + il)*64 + oc*8 + oy*2] = make_uint2(packed[0], packed[1]);
        atomicAdd(&sm.c.s3acc[oc], ssum);
      }
      __syncthreads();
    }
    if (tid < 8) S3P[blockIdx.x*8 + tid] = sm.c.s3acc[tid];
  }
  __threadfence();
  grid.sync();

  // ================= Phase D: t3 reduce + conv4 + bias -> out =================
  {
    {
      int s = 0;
      if (tid < 128) {
        int oc = tid & 7, g = tid >> 3;   // 16 groups
        for (int b = g; b < G; b += 16) s += S3P[b*8 + oc];
        sm.d.red[tid] = s;
      }
    }
    if (tid >= 128 && tid < 148) sm.d.wlb[tid - 128] = ((const uint64_t*)(ws + OFF_WLB))[tid - 128];
    if (tid >= 160 && tid < 170) sm.d.sbl[tid - 160] = ((const float*)(ws + OFF_SBL))[tid - 160];
    __syncthreads();
    if (tid < 8) {
      long long S = 0;
      #pragma unroll
      for (int g = 0; g < 16; ++g) S += (long long)sm.d.red[g*8 + tid];
      const long long N3 = (long long)BATCH * 16;
      long long q = S / N3, r = S % N3;
      long long t = q + (r > 0 ? 1 : 0);
      if (t & 1) t += 1;   // z3 is even
      sm.d.t3[tid] = (int)t;
    }
    __syncthreads();

    for (int img = blockIdx.x*256 + tid; img < BATCH; img += G*256) {
      const uint4* zp = (const uint4*)&Z3w[(size_t)img * 64];
      uint64_t a0 = 0, a1 = 0;
      #pragma unroll
      for (int q = 0; q < 4; ++q) {       // chunk = 16 words = 32 activation bits
        uint32_t mm = 0;
        #pragma unroll
        for (int i = 0; i < 4; ++i) {
          uint4 v = zp[q*4 + i];
          uint32_t w4[4] = {v.x, v.y, v.z, v.w};
          #pragma unroll
          for (int j = 0; j < 4; ++j) {
            int word = q*16 + i*4 + j;
            int th = sm.d.t3[word >> 3];
            int zlo = (int)(short)(w4[j] & 0xFFFFu);
            int zhi = (int)w4[j] >> 16;
            mm |= (uint32_t)(zlo < th) << (2*(i*4+j));
            mm |= (uint32_t)(zhi < th) << (2*(i*4+j)+1);
          }
        }
        if (q < 2) a0 |= (uint64_t)mm << (32*q);
        else       a1 |= (uint64_t)mm << (32*(q-2));
      }
      #pragma unroll
      for (int oc = 0; oc < 10; ++oc) {
        int mism = __popcll(a0 ^ sm.d.wlb[oc*2]) + __popcll(a1 ^ sm.d.wlb[oc*2 + 1]);
        out[(size_t)img*10 + oc] = (float)(128 - 2*mism) + sm.d.sbl[oc];
      }
    }
  }
}

// ----------------------------------------------------------------
extern "C" void kernel_launch(void* const* d_in, const int* in_sizes, int n_in,
                              void* d_out, int out_size, void* d_ws, size_t ws_size,
                              hipStream_t stream) {
  (void)in_sizes; (void)n_in; (void)out_size; (void)ws_size;
  const float* x  = (const float*)d_in[0];
  const float* w1 = (const float*)d_in[1];
  // d_in[2]=b1, d_in[4]=b2, d_in[6]=b3: biases cancel under BN -> unused
  const float* w2 = (const float*)d_in[3];
  const float* w3 = (const float*)d_in[5];
  const float* wl = (const float*)d_in[7];
  const float* bl = (const float*)d_in[8];
  uint8_t* ws = (uint8_t*)d_ws;
  float* out = (float*)d_out;

  int nb = 0;
  if (hipOccupancyMaxActiveBlocksPerMultiprocessor(&nb, fused_bnn, 256, 0) != hipSuccess || nb < 1)
    nb = 2;  // conservative fallback
  long long Gl = (long long)nb * 256;  // 256 CUs on MI355X
  int G = (int)(Gl > NVB ? NVB : Gl);

  void* args[8] = {(void*)&x, (void*)&w1, (void*)&w2, (void*)&w3,
                   (void*)&wl, (void*)&bl, (void*)&ws, (void*)&out};
  hipLaunchCooperativeKernel((const void*)fused_bnn, dim3(G), dim3(256), args, 0, stream);
}

// Round 8
// 318.076 us; speedup vs baseline: 1.5806x; 1.5806x over previous
//
#include <hip/hip_runtime.h>
#include <stdint.h>

#define BATCH 8192
#define NVB   1024

// ws byte offsets
#define OFF_W1R3  0          // uint32[96]   w1 signs, 3 rows x 9 bits per word
#define OFF_W2P   384        // uint32[1440] w2 signs [och 8][kh 9][kw 10 pad] x uint2
#define OFF_W3P   6144       // uint32[864]  w3 signs [oc 8][kh 9][kw 12 pad]
#define OFF_WLB   9600       // uint64[20]   wl signs, 128 bits per oc
#define OFF_SBL   9760       // float[10]    sign(bl)
#define OFF_TPART 9856       // int[1024][81]  layer-1 window-sum partials (per k1 block)
#define OFF_S2P   341632     // int[1024][16]  layer-2 channel-sum partials (per k2 block)
#define OFF_S3P   407168     // int[1024][8]   layer-3 channel-sum partials (per k3 block)
#define OFF_Z2    440320     // uint32[8192][576] : int16 z2 [img][px 144][oc 16]
#define OFF_Z3    38189056   // uint32[8192][32]  : int16 z3 [img][oc 8][px 16]
// total ~40.3 MB

// ---------------------------------------------------------------- K1: distributed weight pack + layer-1 window sums
// grid 1024, 8 images/block. Packing spread over blocks 0..8, <=1 item/thread.
__global__ __launch_bounds__(256) void k1_pack_tsum(const float* __restrict__ x,
                                                    const float* __restrict__ w1,
                                                    const float* __restrict__ w2,
                                                    const float* __restrict__ w3,
                                                    const float* __restrict__ wl,
                                                    const float* __restrict__ bl,
                                                    uint8_t* __restrict__ ws) {
  const int tid = threadIdx.x;
  const int bid = blockIdx.x;
  int* TPART = (int*)(ws + OFF_TPART);

  // ---- distributed packing ----
  if (bid < 4) {              // w2: 648 uint2 items over 4 blocks (162 each)
    uint32_t* W2P = (uint32_t*)(ws + OFF_W2P);
    int e = bid * 162 + tid;
    if (tid < 162) {
      int och = e / 81, k = e % 81, kh = k / 9, kw = k % 9;
      uint32_t m0 = 0, m1 = 0;
      int oc0 = och * 2;
      #pragma unroll
      for (int ic = 0; ic < 32; ++ic) {
        if (w2[(oc0*32 + ic)*81 + k] < 0.f)     m0 |= 1u << ic;
        if (w2[((oc0+1)*32 + ic)*81 + k] < 0.f) m1 |= 1u << ic;
      }
      int idx = ((och*9 + kh)*10 + kw)*2;
      W2P[idx] = m0; W2P[idx+1] = m1;
    }
    if (bid == 0 && tid < 72) {  // zero pad words kw=9
      int idx = (tid*10 + 9)*2;
      W2P[idx] = 0; W2P[idx+1] = 0;
    }
  } else if (bid < 7) {       // w3: 648 items over 3 blocks (216 each)
    uint32_t* W3P = (uint32_t*)(ws + OFF_W3P);
    int e = (bid - 4) * 216 + tid;
    if (tid < 216) {
      int oc = e / 81, k = e % 81, kh = k / 9, kw = k % 9;
      uint32_t m = 0;
      #pragma unroll
      for (int ic = 0; ic < 16; ++ic)
        if (w3[(oc*16 + ic)*81 + k] < 0.f) m |= 1u << ic;
      W3P[(oc*9 + kh)*12 + kw] = m;
    }
    if (bid == 4 && tid < 216) { int row = tid / 3, p = tid % 3; W3P[row*12 + 9 + p] = 0; }
  } else if (bid == 7) {      // w1: 96 words, 27 loads each
    uint32_t* W1R3 = (uint32_t*)(ws + OFF_W1R3);
    if (tid < 96) {
      int oc = tid / 3, i = tid % 3;
      uint32_t m = 0;
      #pragma unroll
      for (int rr = 0; rr < 3; ++rr)
        #pragma unroll
        for (int kw = 0; kw < 9; ++kw)
          if (w1[oc*81 + (3*i+rr)*9 + kw] < 0.f) m |= 1u << (rr*9 + kw);
      W1R3[tid] = m;
    }
  } else if (bid == 8) {      // wl via coalesced ballot (64 consecutive floats = one uint64) + bl
    uint64_t* WLB = (uint64_t*)(ws + OFF_WLB);
    float* SBL = (float*)(ws + OFF_SBL);
    #pragma unroll
    for (int i = 0; i < 5; ++i) {
      int idx = i*256 + tid;              // 1280 floats total
      float v = wl[idx];
      unsigned long long m = __ballot(v < 0.f);
      if ((tid & 63) == 0) WLB[idx >> 6] = m;
    }
    if (tid < 10) SBL[tid] = (bl[tid] >= 0.f) ? 1.f : -1.f;
  }

  // ---- all blocks: layer-1 window sums for 8 images -> TPART[bid] ----
  __shared__ uint32_t rowm[224];
  __shared__ int Tacc[81];
  if (tid < 81) Tacc[tid] = 0;
  __syncthreads();
  const int img0 = bid * 8;
  if (tid < 224) {
    int il = tid / 28, r = tid % 28;
    const float4* xr = (const float4*)(x + (size_t)(img0 + il) * 784 + r * 28);
    uint32_t m = 0;
    #pragma unroll
    for (int j = 0; j < 7; ++j) {
      float4 v = xr[j];
      if (v.x < 0.f) m |= 1u << (j*4+0);
      if (v.y < 0.f) m |= 1u << (j*4+1);
      if (v.z < 0.f) m |= 1u << (j*4+2);
      if (v.w < 0.f) m |= 1u << (j*4+3);
    }
    rowm[tid] = m;
  }
  __syncthreads();
  if (tid < 72) {             // (il, kw): sliding 20-row window of neg counts
    int il = tid / 9, kw = tid % 9;
    int base = il * 28;
    int n9[9];
    int sum20 = 0;
    #pragma unroll
    for (int r = 0; r < 20; ++r) {
      int n = __popc((rowm[base + r] >> kw) & 0xFFFFFu);
      if (r < 9) n9[r] = n;
      sum20 += n;
    }
    atomicAdd(&Tacc[kw], 400 - 2*sum20);
    #pragma unroll
    for (int kh = 1; kh <= 8; ++kh) {
      int nadd = __popc((rowm[base + kh + 19] >> kw) & 0xFFFFFu);
      sum20 += nadd - n9[kh-1];
      atomicAdd(&Tacc[kh*9 + kw], 400 - 2*sum20);
    }
  }
  __syncthreads();
  if (tid < 81) TPART[bid*81 + tid] = Tacc[tid];
}

// ---------------------------------------------------------------- K2: conv1 (recompute) + conv2
#define K2_IMGS 8
__global__ __launch_bounds__(256) void k2_conv12(const float* __restrict__ x,
                                                 uint8_t* __restrict__ ws) {
  const uint32_t* W1R3g = (const uint32_t*)(ws + OFF_W1R3);
  const uint32_t* W2Pg  = (const uint32_t*)(ws + OFF_W2P);
  const int* TPART = (const int*)(ws + OFF_TPART);
  int* S2P = (int*)(ws + OFF_S2P);

  __shared__ uint32_t __attribute__((aligned(16))) rowm[K2_IMGS*28];
  __shared__ uint32_t __attribute__((aligned(16))) w1r3[96];
  __shared__ uint32_t __attribute__((aligned(16))) w2p[1440];
  __shared__ int red[243];
  __shared__ int tlds[81];
  __shared__ int t1s[32];
  __shared__ uint32_t __attribute__((aligned(16))) A1s[K2_IMGS*400];
  __shared__ int s2acc[16];

  const int tid = threadIdx.x;
  const int img0 = blockIdx.x * K2_IMGS;

  for (int e = tid; e < 96; e += 256)   w1r3[e] = W1R3g[e];
  for (int e = tid; e < 1440; e += 256) w2p[e]  = W2Pg[e];
  // Ttot reduction: TPART[1024][81] -> tlds[81], 3 sub-partials per k
  if (tid < 243) {
    int k = tid % 81, sub = tid / 81;
    int s = 0;
    for (int r = sub; r < NVB; r += 3) s += TPART[r*81 + k];
    red[tid] = s;
  }
  if (tid < 16) s2acc[tid] = 0;
  if (tid < K2_IMGS*28) {
    int il = tid / 28, rr = tid % 28;
    const float4* xr = (const float4*)(x + (size_t)(img0 + il) * 784 + rr * 28);
    uint32_t m = 0;
    #pragma unroll
    for (int j = 0; j < 7; ++j) {
      float4 v = xr[j];
      if (v.x < 0.f) m |= 1u << (j*4+0);
      if (v.y < 0.f) m |= 1u << (j*4+1);
      if (v.z < 0.f) m |= 1u << (j*4+2);
      if (v.w < 0.f) m |= 1u << (j*4+3);
    }
    rowm[tid] = m;
  }
  __syncthreads();
  if (tid < 81) tlds[tid] = red[tid] + red[tid+81] + red[tid+162];
  __syncthreads();

  // layer-1 thresholds (odd parity): t1 = smallest odd integer >= S1/N1
  if (tid < 32) {
    long long S = 0;
    for (int kh = 0; kh < 9; ++kh)
      for (int kw = 0; kw < 9; ++kw) {
        int bit = (w1r3[tid*3 + kh/3] >> ((kh%3)*9 + kw)) & 1;
        S += (long long)(1 - 2*bit) * tlds[kh*9 + kw];
      }
    const long long N1 = (long long)BATCH * 400;
    long long q = S / N1, rr = S % N1;
    long long t = q + (rr > 0 ? 1 : 0);
    if ((t & 1) == 0) t += 1;
    t1s[tid] = (int)t;
  }
  __syncthreads();

  // conv1 + binarize -> A1s. Task = (il, oh, 5-ow group): 640 tasks.
  for (int G = tid; G < K2_IMGS*80; G += 256) {
    int il = G / 80, rem = G - il*80;
    int oh = rem >> 2, ow0 = (rem & 3) * 5;
    uint32_t R[9];
    #pragma unroll
    for (int i = 0; i < 9; ++i) R[i] = rowm[il*28 + oh + i];
    uint32_t win[5][3];
    #pragma unroll
    for (int j = 0; j < 5; ++j) {
      int ow = ow0 + j;
      #pragma unroll
      for (int i = 0; i < 3; ++i) {
        uint32_t b0 = (R[3*i]   >> ow) & 0x1FFu;
        uint32_t b1 = (R[3*i+1] >> ow) & 0x1FFu;
        uint32_t b2 = (R[3*i+2] >> ow) & 0x1FFu;
        win[j][i] = b0 | (b1 << 9) | (b2 << 18);
      }
    }
    uint32_t mask[5] = {0,0,0,0,0};
    #pragma unroll
    for (int ocg = 0; ocg < 4; ++ocg) {
      const uint4* wp = (const uint4*)&w1r3[ocg*24];
      uint32_t wr[24];
      #pragma unroll
      for (int q = 0; q < 6; ++q) {
        uint4 v = wp[q];
        wr[q*4+0]=v.x; wr[q*4+1]=v.y; wr[q*4+2]=v.z; wr[q*4+3]=v.w;
      }
      #pragma unroll
      for (int o8 = 0; o8 < 8; ++o8) {
        int oc = ocg*8 + o8;
        int t = t1s[oc];
        #pragma unroll
        for (int j = 0; j < 5; ++j) {
          int mm = __popc(win[j][0] ^ wr[o8*3])
                 + __popc(win[j][1] ^ wr[o8*3+1])
                 + __popc(win[j][2] ^ wr[o8*3+2]);
          mask[j] |= (uint32_t)((81 - 2*mm) < t) << oc;
        }
      }
    }
    #pragma unroll
    for (int j = 0; j < 5; ++j) A1s[il*400 + oh*20 + ow0 + j] = mask[j];
  }
  __syncthreads();

  // conv2: task = (il, oy, oc-pair): 768 tasks, 3 per thread.
  uint32_t* Z2w = (uint32_t*)(ws + OFF_Z2);
  const int och = tid & 7, oc0 = och << 1;
  int sl0 = 0, sl1 = 0;
  for (int r = 0; r < 3; ++r) {
    int G = tid + r*256;
    int il = G / 96, rem = G - il*96;
    int oy = rem >> 3;
    const uint32_t* A = &A1s[il*400 + oy*20];
    int acc0[12], acc1[12];
    #pragma unroll
    for (int p = 0; p < 12; ++p) { acc0[p] = 0; acc1[p] = 0; }
    for (int kh = 0; kh < 9; ++kh) {
      const uint4* ar = (const uint4*)(A + kh*20);
      uint32_t a[20];
      #pragma unroll
      for (int q = 0; q < 5; ++q) {
        uint4 v = ar[q];
        a[q*4+0]=v.x; a[q*4+1]=v.y; a[q*4+2]=v.z; a[q*4+3]=v.w;
      }
      const uint4* wp4 = (const uint4*)&w2p[(och*9 + kh)*20];
      uint32_t wbuf[20];
      #pragma unroll
      for (int q = 0; q < 5; ++q) {
        uint4 v = wp4[q];
        wbuf[q*4+0]=v.x; wbuf[q*4+1]=v.y; wbuf[q*4+2]=v.z; wbuf[q*4+3]=v.w;
      }
      #pragma unroll
      for (int kw = 0; kw < 9; ++kw) {
        uint32_t w0 = wbuf[2*kw], w1v = wbuf[2*kw+1];
        #pragma unroll
        for (int px = 0; px < 12; ++px) {
          acc0[px] += __popc(a[kw+px] ^ w0);
          acc1[px] += __popc(a[kw+px] ^ w1v);
        }
      }
    }
    size_t wbase = (size_t)(img0+il)*1152 + (size_t)oy*96 + och;
    #pragma unroll
    for (int px = 0; px < 12; ++px) {
      int z0 = 2592 - 2*acc0[px], z1v = 2592 - 2*acc1[px];
      sl0 += z0; sl1 += z1v;
      Z2w[wbase + px*8] = (uint32_t)(uint16_t)(int16_t)z0
                        | ((uint32_t)(uint16_t)(int16_t)z1v << 16);
    }
  }
  atomicAdd(&s2acc[oc0],   sl0);
  atomicAdd(&s2acc[oc0+1], sl1);
  __syncthreads();
  if (tid < 16) S2P[blockIdx.x*16 + tid] = s2acc[tid];
}

// ---------------------------------------------------------------- K3: t2-reduce + binarize + conv3
#define K3_IMGS 8
__global__ __launch_bounds__(256) void k3_conv3(uint8_t* __restrict__ ws) {
  const int* S2P = (const int*)(ws + OFF_S2P);
  const uint32_t* W3Pg = (const uint32_t*)(ws + OFF_W3P);
  const uint32_t* Z2w = (const uint32_t*)(ws + OFF_Z2);
  uint32_t* Z3w = (uint32_t*)(ws + OFF_Z3);
  int* S3P = (int*)(ws + OFF_S3P);

  __shared__ uint32_t __attribute__((aligned(16))) w3p[864];
  __shared__ int part[256];
  __shared__ int t2s[16];
  __shared__ uint32_t __attribute__((aligned(16))) A2[K3_IMGS*144];
  __shared__ int s3acc[8];

  const int tid = threadIdx.x;
  const int img0 = blockIdx.x * K3_IMGS;

  {
    int c = tid & 15, g = tid >> 4;
    int s = 0;
    for (int j = 0; j < 64; ++j) s += S2P[(g + 16*j)*16 + c];
    part[tid] = s;
  }
  for (int e = tid; e < 864; e += 256) w3p[e] = W3Pg[e];
  if (tid < 8) s3acc[tid] = 0;
  __syncthreads();
  if (tid < 16) {
    long long S = 0;
    #pragma unroll
    for (int g = 0; g < 16; ++g) S += (long long)part[g*16 + tid];
    const long long N2 = (long long)BATCH * 144;
    long long q = S / N2, r = S % N2;
    long long t = q + (r > 0 ? 1 : 0);
    if (t & 1) t += 1;   // z2 is even
    t2s[tid] = (int)t;
  }
  __syncthreads();

  // binarize z2 -> A2 masks. 8 imgs x 144 px, coalesced 32B/px.
  for (int idx = tid; idx < K3_IMGS*144; idx += 256) {
    const uint4* zp = (const uint4*)&Z2w[(size_t)(img0 + idx/144)*1152 + (size_t)(idx%144)*8];
    uint4 v0 = zp[0], v1 = zp[1];
    uint32_t zz[8] = {v0.x,v0.y,v0.z,v0.w, v1.x,v1.y,v1.z,v1.w};
    uint32_t m = 0;
    #pragma unroll
    for (int i = 0; i < 8; ++i) {
      int zlo = (int)(short)(zz[i] & 0xFFFFu);
      int zhi = (int)zz[i] >> 16;
      m |= (uint32_t)(zlo < t2s[2*i])   << (2*i);
      m |= (uint32_t)(zhi < t2s[2*i+1]) << (2*i+1);
    }
    A2[idx] = m;
  }
  __syncthreads();

  // conv3: task = (il, oc, oy): tid = il*32 + oc*4 + oy, 4 px per thread.
  const int il = tid >> 5, oc = (tid >> 2) & 7, oy = tid & 3;
  int acc[4] = {0, 0, 0, 0};
  #pragma unroll
  for (int kh = 0; kh < 9; ++kh) {
    const uint4* ar = (const uint4*)&A2[il*144 + (oy + kh)*12];
    uint4 v0 = ar[0], v1 = ar[1], v2 = ar[2];
    uint32_t a[12] = {v0.x,v0.y,v0.z,v0.w, v1.x,v1.y,v1.z,v1.w, v2.x,v2.y,v2.z,v2.w};
    const uint4* wr = (const uint4*)&w3p[(oc*9 + kh)*12];
    uint4 w0 = wr[0], w1v = wr[1], w2v = wr[2];
    uint32_t w[9] = {w0.x,w0.y,w0.z,w0.w, w1v.x,w1v.y,w1v.z,w1v.w, w2v.x};
    #pragma unroll
    for (int ox = 0; ox < 4; ++ox) {
      #pragma unroll
      for (int kw = 0; kw < 9; ++kw) acc[ox] += __popc(a[ox+kw] ^ w[kw]);
    }
  }
  int ssum = 0;
  uint32_t packed[2];
  #pragma unroll
  for (int h = 0; h < 2; ++h) {
    int za = 1296 - 2*acc[2*h], zb = 1296 - 2*acc[2*h+1];
    ssum += za + zb;
    packed[h] = (uint32_t)(uint16_t)(int16_t)za | ((uint32_t)(uint16_t)(int16_t)zb << 16);
  }
  *(uint2*)&Z3w[(size_t)(img0 + il)*64 + oc*8 + oy*2] = make_uint2(packed[0], packed[1]);
  atomicAdd(&s3acc[oc], ssum);
  __syncthreads();
  if (tid < 8) S3P[blockIdx.x*8 + tid] = s3acc[tid];
}

// ---------------------------------------------------------------- K4: t3-reduce + conv4 + bias -> out
// grid 128 x 64 threads: one image per thread.
__global__ __launch_bounds__(64) void k4_final(uint8_t* __restrict__ ws,
                                               float* __restrict__ out) {
  const uint32_t* Z3w = (const uint32_t*)(ws + OFF_Z3);
  const int* S3P = (const int*)(ws + OFF_S3P);
  const uint64_t* WLBg = (const uint64_t*)(ws + OFF_WLB);
  const float* SBLg = (const float*)(ws + OFF_SBL);
  __shared__ int red[64];
  __shared__ int t3[8];
  __shared__ uint64_t wlb[20];
  __shared__ float sbl[10];
  const int tid = threadIdx.x;
  {
    int oc = tid & 7, g = tid >> 3;   // 8 groups over 1024 partials
    int s = 0;
    for (int b = g; b < NVB; b += 8) s += S3P[b*8 + oc];
    red[tid] = s;
  }
  if (tid < 20) wlb[tid] = WLBg[tid];
  if (tid >= 32 && tid < 42) sbl[tid - 32] = SBLg[tid - 32];
  __syncthreads();
  if (tid < 8) {
    long long S = 0;
    #pragma unroll
    for (int g = 0; g < 8; ++g) S += (long long)red[g*8 + tid];
    const long long N3 = (long long)BATCH * 16;
    long long q = S / N3, r = S % N3;
    long long t = q + (r > 0 ? 1 : 0);
    if (t & 1) t += 1;   // z3 is even
    t3[tid] = (int)t;
  }
  __syncthreads();
  int img = blockIdx.x * 64 + tid;
  const uint4* zp = (const uint4*)&Z3w[(size_t)img * 64];
  uint32_t zz[64];
  #pragma unroll
  for (int q = 0; q < 16; ++q) {
    uint4 v = zp[q];
    zz[q*4+0]=v.x; zz[q*4+1]=v.y; zz[q*4+2]=v.z; zz[q*4+3]=v.w;
  }
  uint64_t a0 = 0, a1 = 0;
  #pragma unroll
  for (int j = 0; j < 64; ++j) {
    int z = (j & 1) ? ((int)zz[j>>1] >> 16) : (int)(short)(zz[j>>1] & 0xFFFFu);
    a0 |= (uint64_t)(z < t3[j >> 4]) << j;
  }
  #pragma unroll
  for (int j = 0; j < 64; ++j) {
    int z = (j & 1) ? ((int)zz[32 + (j>>1)] >> 16) : (int)(short)(zz[32 + (j>>1)] & 0xFFFFu);
    a1 |= (uint64_t)(z < t3[(64 + j) >> 4]) << j;
  }
  #pragma unroll
  for (int oc = 0; oc < 10; ++oc) {
    int mism = __popcll(a0 ^ wlb[oc*2]) + __popcll(a1 ^ wlb[oc*2 + 1]);
    out[(size_t)img*10 + oc] = (float)(128 - 2*mism) + sbl[oc];
  }
}

// ----------------------------------------------------------------
extern "C" void kernel_launch(void* const* d_in, const int* in_sizes, int n_in,
                              void* d_out, int out_size, void* d_ws, size_t ws_size,
                              hipStream_t stream) {
  (void)in_sizes; (void)n_in; (void)out_size; (void)ws_size;
  const float* x  = (const float*)d_in[0];
  const float* w1 = (const float*)d_in[1];
  // d_in[2]=b1, d_in[4]=b2, d_in[6]=b3: biases cancel under BN -> unused
  const float* w2 = (const float*)d_in[3];
  const float* w3 = (const float*)d_in[5];
  const float* wl = (const float*)d_in[7];
  const float* bl = (const float*)d_in[8];
  uint8_t* ws = (uint8_t*)d_ws;
  float* out = (float*)d_out;

  // no memset: TPART/S2P/S3P are fully written before being read
  k1_pack_tsum<<<1024, 256, 0, stream>>>(x, w1, w2, w3, wl, bl, ws);
  k2_conv12<<<1024, 256, 0, stream>>>(x, ws);
  k3_conv3<<<1024, 256, 0, stream>>>(ws);
  k4_final<<<128, 64, 0, stream>>>(ws, out);
}

// Round 9
// 271.784 us; speedup vs baseline: 1.8498x; 1.1703x over previous
//
#include <hip/hip_runtime.h>
#include <stdint.h>

#define BATCH 8192
#define NVB   1024

// ws byte offsets
#define OFF_W1R3  0          // uint32[96]   w1 signs, 3 rows x 9 bits per word
#define OFF_W2P   384        // uint32[1440] w2 signs [och 8][kh 9][kw 10 pad] x uint2
#define OFF_W3P   6144       // uint32[864]  w3 signs [oc 8][kh 9][kw 12 pad]
#define OFF_WLB   9600       // uint64[20]   wl signs, 128 bits per oc
#define OFF_SBL   9760       // float[10]    sign(bl)
#define OFF_TTOT  9856       // int32[81]    layer-1 window sums (global atomics, memset to 0)
#define OFF_S2P   341632     // int[1024][16]  layer-2 channel-sum partials (per k2 block)
#define OFF_S3P   407168     // int[1024][8]   layer-3 channel-sum partials (per k3 block)
#define OFF_Z2    440320     // uint32[8192][576] : int16 z2 [img][px 144][oc 16]
#define OFF_Z3    38189056   // uint32[8192][32]  : int16 z3 [img][oc 8][px 16]
// total ~40.3 MB

// ---------------------------------------------------------------- K1: distributed weight pack + layer-1 window sums
// grid 1024, 8 images/block. Packing spread over blocks 0..8, <=1 item/thread.
__global__ __launch_bounds__(256) void k1_pack_tsum(const float* __restrict__ x,
                                                    const float* __restrict__ w1,
                                                    const float* __restrict__ w2,
                                                    const float* __restrict__ w3,
                                                    const float* __restrict__ wl,
                                                    const float* __restrict__ bl,
                                                    uint8_t* __restrict__ ws) {
  const int tid = threadIdx.x;
  const int bid = blockIdx.x;
  int* Ttot = (int*)(ws + OFF_TTOT);

  // ---- distributed packing ----
  if (bid < 4) {              // w2: 648 uint2 items over 4 blocks (162 each)
    uint32_t* W2P = (uint32_t*)(ws + OFF_W2P);
    int e = bid * 162 + tid;
    if (tid < 162) {
      int och = e / 81, k = e % 81, kh = k / 9, kw = k % 9;
      uint32_t m0 = 0, m1 = 0;
      int oc0 = och * 2;
      #pragma unroll
      for (int ic = 0; ic < 32; ++ic) {
        if (w2[(oc0*32 + ic)*81 + k] < 0.f)     m0 |= 1u << ic;
        if (w2[((oc0+1)*32 + ic)*81 + k] < 0.f) m1 |= 1u << ic;
      }
      int idx = ((och*9 + kh)*10 + kw)*2;
      W2P[idx] = m0; W2P[idx+1] = m1;
    }
    if (bid == 0 && tid < 72) {  // zero pad words kw=9
      int idx = (tid*10 + 9)*2;
      W2P[idx] = 0; W2P[idx+1] = 0;
    }
  } else if (bid < 7) {       // w3: 648 items over 3 blocks (216 each)
    uint32_t* W3P = (uint32_t*)(ws + OFF_W3P);
    int e = (bid - 4) * 216 + tid;
    if (tid < 216) {
      int oc = e / 81, k = e % 81, kh = k / 9, kw = k % 9;
      uint32_t m = 0;
      #pragma unroll
      for (int ic = 0; ic < 16; ++ic)
        if (w3[(oc*16 + ic)*81 + k] < 0.f) m |= 1u << ic;
      W3P[(oc*9 + kh)*12 + kw] = m;
    }
    if (bid == 4 && tid < 216) { int row = tid / 3, p = tid % 3; W3P[row*12 + 9 + p] = 0; }
  } else if (bid == 7) {      // w1: 96 words, 27 loads each
    uint32_t* W1R3 = (uint32_t*)(ws + OFF_W1R3);
    if (tid < 96) {
      int oc = tid / 3, i = tid % 3;
      uint32_t m = 0;
      #pragma unroll
      for (int rr = 0; rr < 3; ++rr)
        #pragma unroll
        for (int kw = 0; kw < 9; ++kw)
          if (w1[oc*81 + (3*i+rr)*9 + kw] < 0.f) m |= 1u << (rr*9 + kw);
      W1R3[tid] = m;
    }
  } else if (bid == 8) {      // wl via coalesced ballot (64 consecutive floats = one uint64) + bl
    uint64_t* WLB = (uint64_t*)(ws + OFF_WLB);
    float* SBL = (float*)(ws + OFF_SBL);
    #pragma unroll
    for (int i = 0; i < 5; ++i) {
      int idx = i*256 + tid;              // 1280 floats total
      float v = wl[idx];
      unsigned long long m = __ballot(v < 0.f);
      if ((tid & 63) == 0) WLB[idx >> 6] = m;
    }
    if (tid < 10) SBL[tid] = (bl[tid] >= 0.f) ? 1.f : -1.f;
  }

  // ---- all blocks: layer-1 window sums for 8 images -> atomicAdd Ttot ----
  __shared__ uint32_t rowm[224];
  __shared__ int Tacc[81];
  if (tid < 81) Tacc[tid] = 0;
  __syncthreads();
  const int img0 = bid * 8;
  if (tid < 224) {
    int il = tid / 28, r = tid % 28;
    const float4* xr = (const float4*)(x + (size_t)(img0 + il) * 784 + r * 28);
    uint32_t m = 0;
    #pragma unroll
    for (int j = 0; j < 7; ++j) {
      float4 v = xr[j];
      if (v.x < 0.f) m |= 1u << (j*4+0);
      if (v.y < 0.f) m |= 1u << (j*4+1);
      if (v.z < 0.f) m |= 1u << (j*4+2);
      if (v.w < 0.f) m |= 1u << (j*4+3);
    }
    rowm[tid] = m;
  }
  __syncthreads();
  if (tid < 72) {             // (il, kw): sliding 20-row window of neg counts
    int il = tid / 9, kw = tid % 9;
    int base = il * 28;
    int n9[9];
    int sum20 = 0;
    #pragma unroll
    for (int r = 0; r < 20; ++r) {
      int n = __popc((rowm[base + r] >> kw) & 0xFFFFFu);
      if (r < 9) n9[r] = n;
      sum20 += n;
    }
    atomicAdd(&Tacc[kw], 400 - 2*sum20);
    #pragma unroll
    for (int kh = 1; kh <= 8; ++kh) {
      int nadd = __popc((rowm[base + kh + 19] >> kw) & 0xFFFFFu);
      sum20 += nadd - n9[kh-1];
      atomicAdd(&Tacc[kh*9 + kw], 400 - 2*sum20);
    }
  }
  __syncthreads();
  if (tid < 81) atomicAdd(&Ttot[tid], Tacc[tid]);
}

// ---------------------------------------------------------------- K2: conv1 (recompute) + conv2  [R6-proven body]
#define K2_IMGS 8
__global__ __launch_bounds__(256) void k2_conv12(const float* __restrict__ x,
                                                 uint8_t* __restrict__ ws) {
  const uint32_t* W1R3g = (const uint32_t*)(ws + OFF_W1R3);
  const uint32_t* W2Pg  = (const uint32_t*)(ws + OFF_W2P);
  const int* Ttot = (const int*)(ws + OFF_TTOT);
  int* S2P = (int*)(ws + OFF_S2P);

  __shared__ uint32_t __attribute__((aligned(16))) rowm[K2_IMGS*28];
  __shared__ uint32_t __attribute__((aligned(16))) w1r3[96];
  __shared__ uint32_t __attribute__((aligned(16))) w2p[1440];
  __shared__ int tlds[81];
  __shared__ int t1s[32];
  __shared__ uint32_t __attribute__((aligned(16))) A1s[K2_IMGS*400];
  __shared__ int s2acc[16];

  const int tid = threadIdx.x;
  const int img0 = blockIdx.x * K2_IMGS;

  for (int e = tid; e < 96; e += 256)   w1r3[e] = W1R3g[e];
  for (int e = tid; e < 1440; e += 256) w2p[e]  = W2Pg[e];
  if (tid < 81) tlds[tid] = Ttot[tid];
  if (tid < 16) s2acc[tid] = 0;
  if (tid < K2_IMGS*28) {
    int il = tid / 28, rr = tid % 28;
    const float4* xr = (const float4*)(x + (size_t)(img0 + il) * 784 + rr * 28);
    uint32_t m = 0;
    #pragma unroll
    for (int j = 0; j < 7; ++j) {
      float4 v = xr[j];
      if (v.x < 0.f) m |= 1u << (j*4+0);
      if (v.y < 0.f) m |= 1u << (j*4+1);
      if (v.z < 0.f) m |= 1u << (j*4+2);
      if (v.w < 0.f) m |= 1u << (j*4+3);
    }
    rowm[tid] = m;
  }
  __syncthreads();

  // layer-1 thresholds (odd parity): t1 = smallest odd integer >= S1/N1
  if (tid < 32) {
    long long S = 0;
    for (int kh = 0; kh < 9; ++kh)
      for (int kw = 0; kw < 9; ++kw) {
        int bit = (w1r3[tid*3 + kh/3] >> ((kh%3)*9 + kw)) & 1;
        S += (long long)(1 - 2*bit) * tlds[kh*9 + kw];
      }
    const long long N1 = (long long)BATCH * 400;
    long long q = S / N1, rr = S % N1;
    long long t = q + (rr > 0 ? 1 : 0);
    if ((t & 1) == 0) t += 1;
    t1s[tid] = (int)t;
  }
  __syncthreads();

  // conv1 + binarize -> A1s. Task = (il, oh, 5-ow group): 640 tasks.
  for (int G = tid; G < K2_IMGS*80; G += 256) {
    int il = G / 80, rem = G - il*80;
    int oh = rem >> 2, ow0 = (rem & 3) * 5;
    uint32_t R[9];
    #pragma unroll
    for (int i = 0; i < 9; ++i) R[i] = rowm[il*28 + oh + i];
    uint32_t win[5][3];
    #pragma unroll
    for (int j = 0; j < 5; ++j) {
      int ow = ow0 + j;
      #pragma unroll
      for (int i = 0; i < 3; ++i) {
        uint32_t b0 = (R[3*i]   >> ow) & 0x1FFu;
        uint32_t b1 = (R[3*i+1] >> ow) & 0x1FFu;
        uint32_t b2 = (R[3*i+2] >> ow) & 0x1FFu;
        win[j][i] = b0 | (b1 << 9) | (b2 << 18);
      }
    }
    uint32_t mask[5] = {0,0,0,0,0};
    #pragma unroll
    for (int ocg = 0; ocg < 4; ++ocg) {
      const uint4* wp = (const uint4*)&w1r3[ocg*24];
      uint32_t wr[24];
      #pragma unroll
      for (int q = 0; q < 6; ++q) {
        uint4 v = wp[q];
        wr[q*4+0]=v.x; wr[q*4+1]=v.y; wr[q*4+2]=v.z; wr[q*4+3]=v.w;
      }
      #pragma unroll
      for (int o8 = 0; o8 < 8; ++o8) {
        int oc = ocg*8 + o8;
        int t = t1s[oc];
        #pragma unroll
        for (int j = 0; j < 5; ++j) {
          int mm = __popc(win[j][0] ^ wr[o8*3])
                 + __popc(win[j][1] ^ wr[o8*3+1])
                 + __popc(win[j][2] ^ wr[o8*3+2]);
          mask[j] |= (uint32_t)((81 - 2*mm) < t) << oc;
        }
      }
    }
    #pragma unroll
    for (int j = 0; j < 5; ++j) A1s[il*400 + oh*20 + ow0 + j] = mask[j];
  }
  __syncthreads();

  // conv2: task = (il, oy, oc-pair): 768 tasks, 3 per thread.
  uint32_t* Z2w = (uint32_t*)(ws + OFF_Z2);
  const int och = tid & 7, oc0 = och << 1;
  int sl0 = 0, sl1 = 0;
  for (int r = 0; r < 3; ++r) {
    int G = tid + r*256;
    int il = G / 96, rem = G - il*96;
    int oy = rem >> 3;
    const uint32_t* A = &A1s[il*400 + oy*20];
    int acc0[12], acc1[12];
    #pragma unroll
    for (int p = 0; p < 12; ++p) { acc0[p] = 0; acc1[p] = 0; }
    for (int kh = 0; kh < 9; ++kh) {
      const uint4* ar = (const uint4*)(A + kh*20);
      uint32_t a[20];
      #pragma unroll
      for (int q = 0; q < 5; ++q) {
        uint4 v = ar[q];
        a[q*4+0]=v.x; a[q*4+1]=v.y; a[q*4+2]=v.z; a[q*4+3]=v.w;
      }
      const uint4* wp4 = (const uint4*)&w2p[(och*9 + kh)*20];
      uint32_t wbuf[20];
      #pragma unroll
      for (int q = 0; q < 5; ++q) {
        uint4 v = wp4[q];
        wbuf[q*4+0]=v.x; wbuf[q*4+1]=v.y; wbuf[q*4+2]=v.z; wbuf[q*4+3]=v.w;
      }
      #pragma unroll
      for (int kw = 0; kw < 9; ++kw) {
        uint32_t w0 = wbuf[2*kw], w1v = wbuf[2*kw+1];
        #pragma unroll
        for (int px = 0; px < 12; ++px) {
          acc0[px] += __popc(a[kw+px] ^ w0);
          acc1[px] += __popc(a[kw+px] ^ w1v);
        }
      }
    }
    size_t wbase = (size_t)(img0+il)*1152 + (size_t)oy*96 + och;
    #pragma unroll
    for (int px = 0; px < 12; ++px) {
      int z0 = 2592 - 2*acc0[px], z1v = 2592 - 2*acc1[px];
      sl0 += z0; sl1 += z1v;
      Z2w[wbase + px*8] = (uint32_t)(uint16_t)(int16_t)z0
                        | ((uint32_t)(uint16_t)(int16_t)z1v << 16);
    }
  }
  atomicAdd(&s2acc[oc0],   sl0);
  atomicAdd(&s2acc[oc0+1], sl1);
  __syncthreads();
  if (tid < 16) S2P[blockIdx.x*16 + tid] = s2acc[tid];
}

// ---------------------------------------------------------------- K3: t2-reduce + binarize + conv3
#define K3_IMGS 8
__global__ __launch_bounds__(256) void k3_conv3(uint8_t* __restrict__ ws) {
  const int* S2P = (const int*)(ws + OFF_S2P);
  const uint32_t* W3Pg = (const uint32_t*)(ws + OFF_W3P);
  const uint32_t* Z2w = (const uint32_t*)(ws + OFF_Z2);
  uint32_t* Z3w = (uint32_t*)(ws + OFF_Z3);
  int* S3P = (int*)(ws + OFF_S3P);

  __shared__ uint32_t __attribute__((aligned(16))) w3p[864];
  __shared__ int part[256];
  __shared__ int t2s[16];
  __shared__ uint32_t __attribute__((aligned(16))) A2[K3_IMGS*144];
  __shared__ int s3acc[8];

  const int tid = threadIdx.x;
  const int img0 = blockIdx.x * K3_IMGS;

  {
    int c = tid & 15, g = tid >> 4;
    int s = 0;
    for (int j = 0; j < 64; ++j) s += S2P[(g + 16*j)*16 + c];
    part[tid] = s;
  }
  for (int e = tid; e < 864; e += 256) w3p[e] = W3Pg[e];
  if (tid < 8) s3acc[tid] = 0;
  __syncthreads();
  if (tid < 16) {
    long long S = 0;
    #pragma unroll
    for (int g = 0; g < 16; ++g) S += (long long)part[g*16 + tid];
    const long long N2 = (long long)BATCH * 144;
    long long q = S / N2, r = S % N2;
    long long t = q + (r > 0 ? 1 : 0);
    if (t & 1) t += 1;   // z2 is even
    t2s[tid] = (int)t;
  }
  __syncthreads();

  // binarize z2 -> A2 masks. 8 imgs x 144 px, coalesced 32B/px.
  for (int idx = tid; idx < K3_IMGS*144; idx += 256) {
    const uint4* zp = (const uint4*)&Z2w[(size_t)(img0 + idx/144)*1152 + (size_t)(idx%144)*8];
    uint4 v0 = zp[0], v1 = zp[1];
    uint32_t zz[8] = {v0.x,v0.y,v0.z,v0.w, v1.x,v1.y,v1.z,v1.w};
    uint32_t m = 0;
    #pragma unroll
    for (int i = 0; i < 8; ++i) {
      int zlo = (int)(short)(zz[i] & 0xFFFFu);
      int zhi = (int)zz[i] >> 16;
      m |= (uint32_t)(zlo < t2s[2*i])   << (2*i);
      m |= (uint32_t)(zhi < t2s[2*i+1]) << (2*i+1);
    }
    A2[idx] = m;
  }
  __syncthreads();

  // conv3: task = (il, oc, oy): tid = il*32 + oc*4 + oy, 4 px per thread.
  const int il = tid >> 5, oc = (tid >> 2) & 7, oy = tid & 3;
  int acc[4] = {0, 0, 0, 0};
  #pragma unroll
  for (int kh = 0; kh < 9; ++kh) {
    const uint4* ar = (const uint4*)&A2[il*144 + (oy + kh)*12];
    uint4 v0 = ar[0], v1 = ar[1], v2 = ar[2];
    uint32_t a[12] = {v0.x,v0.y,v0.z,v0.w, v1.x,v1.y,v1.z,v1.w, v2.x,v2.y,v2.z,v2.w};
    const uint4* wr = (const uint4*)&w3p[(oc*9 + kh)*12];
    uint4 w0 = wr[0], w1v = wr[1], w2v = wr[2];
    uint32_t w[9] = {w0.x,w0.y,w0.z,w0.w, w1v.x,w1v.y,w1v.z,w1v.w, w2v.x};
    #pragma unroll
    for (int ox = 0; ox < 4; ++ox) {
      #pragma unroll
      for (int kw = 0; kw < 9; ++kw) acc[ox] += __popc(a[ox+kw] ^ w[kw]);
    }
  }
  int ssum = 0;
  uint32_t packed[2];
  #pragma unroll
  for (int h = 0; h < 2; ++h) {
    int za = 1296 - 2*acc[2*h], zb = 1296 - 2*acc[2*h+1];
    ssum += za + zb;
    packed[h] = (uint32_t)(uint16_t)(int16_t)za | ((uint32_t)(uint16_t)(int16_t)zb << 16);
  }
  *(uint2*)&Z3w[(size_t)(img0 + il)*64 + oc*8 + oy*2] = make_uint2(packed[0], packed[1]);
  atomicAdd(&s3acc[oc], ssum);
  __syncthreads();
  if (tid < 8) S3P[blockIdx.x*8 + tid] = s3acc[tid];
}

// ---------------------------------------------------------------- K4: t3-reduce + conv4 + bias -> out
__global__ __launch_bounds__(64) void k4_final(uint8_t* __restrict__ ws,
                                               float* __restrict__ out) {
  const uint32_t* Z3w = (const uint32_t*)(ws + OFF_Z3);
  const int* S3P = (const int*)(ws + OFF_S3P);
  const uint64_t* WLBg = (const uint64_t*)(ws + OFF_WLB);
  const float* SBLg = (const float*)(ws + OFF_SBL);
  __shared__ int red[64];
  __shared__ int t3[8];
  __shared__ uint64_t wlb[20];
  __shared__ float sbl[10];
  const int tid = threadIdx.x;
  {
    int oc = tid & 7, g = tid >> 3;   // 8 groups over 1024 partials
    int s = 0;
    for (int b = g; b < NVB; b += 8) s += S3P[b*8 + oc];
    red[tid] = s;
  }
  if (tid < 20) wlb[tid] = WLBg[tid];
  if (tid >= 32 && tid < 42) sbl[tid - 32] = SBLg[tid - 32];
  __syncthreads();
  if (tid < 8) {
    long long S = 0;
    #pragma unroll
    for (int g = 0; g < 8; ++g) S += (long long)red[g*8 + tid];
    const long long N3 = (long long)BATCH * 16;
    long long q = S / N3, r = S % N3;
    long long t = q + (r > 0 ? 1 : 0);
    if (t & 1) t += 1;   // z3 is even
    t3[tid] = (int)t;
  }
  __syncthreads();
  int img = blockIdx.x * 64 + tid;
  const uint4* zp = (const uint4*)&Z3w[(size_t)img * 64];
  uint32_t zz[64];
  #pragma unroll
  for (int q = 0; q < 16; ++q) {
    uint4 v = zp[q];
    zz[q*4+0]=v.x; zz[q*4+1]=v.y; zz[q*4+2]=v.z; zz[q*4+3]=v.w;
  }
  uint64_t a0 = 0, a1 = 0;
  #pragma unroll
  for (int j = 0; j < 64; ++j) {
    int z = (j & 1) ? ((int)zz[j>>1] >> 16) : (int)(short)(zz[j>>1] & 0xFFFFu);
    a0 |= (uint64_t)(z < t3[j >> 4]) << j;
  }
  #pragma unroll
  for (int j = 0; j < 64; ++j) {
    int z = (j & 1) ? ((int)zz[32 + (j>>1)] >> 16) : (int)(short)(zz[32 + (j>>1)] & 0xFFFFu);
    a1 |= (uint64_t)(z < t3[(64 + j) >> 4]) << j;
  }
  #pragma unroll
  for (int oc = 0; oc < 10; ++oc) {
    int mism = __popcll(a0 ^ wlb[oc*2]) + __popcll(a1 ^ wlb[oc*2 + 1]);
    out[(size_t)img*10 + oc] = (float)(128 - 2*mism) + sbl[oc];
  }
}

// ----------------------------------------------------------------
extern "C" void kernel_launch(void* const* d_in, const int* in_sizes, int n_in,
                              void* d_out, int out_size, void* d_ws, size_t ws_size,
                              hipStream_t stream) {
  (void)in_sizes; (void)n_in; (void)out_size; (void)ws_size;
  const float* x  = (const float*)d_in[0];
  const float* w1 = (const float*)d_in[1];
  // d_in[2]=b1, d_in[4]=b2, d_in[6]=b3: biases cancel under BN -> unused
  const float* w2 = (const float*)d_in[3];
  const float* w3 = (const float*)d_in[5];
  const float* wl = (const float*)d_in[7];
  const float* bl = (const float*)d_in[8];
  uint8_t* ws = (uint8_t*)d_ws;
  float* out = (float*)d_out;

  // zero Ttot accumulator (ws is poisoned 0xAA each call); S2P/S3P are fully overwritten
  hipMemsetAsync(ws + OFF_TTOT, 0, 324, stream);
  k1_pack_tsum<<<1024, 256, 0, stream>>>(x, w1, w2, w3, wl, bl, ws);
  k2_conv12<<<1024, 256, 0, stream>>>(x, ws);
  k3_conv3<<<1024, 256, 0, stream>>>(ws);
  k4_final<<<128, 64, 0, stream>>>(ws, out);
}

// Round 10
// 259.208 us; speedup vs baseline: 1.9395x; 1.0485x over previous
//
#include <hip/hip_runtime.h>
#include <stdint.h>

#define BATCH 8192
#define NVB   1024

// ws byte offsets
#define OFF_W1R3  0          // uint32[96]   w1 signs, 3 rows x 9 bits per word
#define OFF_W2P   384        // uint32[1440] w2 signs [och 8][kh 9][kw 10 pad] x uint2
#define OFF_W3P   6144       // uint32[864]  w3 signs [oc 8][kh 9][kw 12 pad]
#define OFF_WLB   9600       // uint64[20]   wl signs, 128 bits per oc
#define OFF_SBL   9760       // float[10]    sign(bl)
#define OFF_TTOT  9856       // int32[81]    layer-1 window sums (global atomics, memset to 0)
#define OFF_S2P   341632     // int[1024][16]  layer-2 channel-sum partials (per k2 block)
#define OFF_S3P   407168     // int[256][8]    layer-3 channel-sum partials (per k3 block)
#define OFF_Z2    440320     // uint32[8192][576] : int16 z2 [img][px 144][oc 16]
#define OFF_Z3    38189056   // uint32[8192][32]  : int16 z3 [img][oc 8][px 16]
// total ~40.3 MB

// ---------------------------------------------------------------- K1: distributed weight pack + layer-1 window sums
// grid 1024, 8 images/block. Packing spread over blocks 0..8, <=1 item/thread.
__global__ __launch_bounds__(256) void k1_pack_tsum(const float* __restrict__ x,
                                                    const float* __restrict__ w1,
                                                    const float* __restrict__ w2,
                                                    const float* __restrict__ w3,
                                                    const float* __restrict__ wl,
                                                    const float* __restrict__ bl,
                                                    uint8_t* __restrict__ ws) {
  const int tid = threadIdx.x;
  const int bid = blockIdx.x;
  int* Ttot = (int*)(ws + OFF_TTOT);

  // ---- distributed packing ----
  if (bid < 4) {              // w2: 648 uint2 items over 4 blocks (162 each)
    uint32_t* W2P = (uint32_t*)(ws + OFF_W2P);
    int e = bid * 162 + tid;
    if (tid < 162) {
      int och = e / 81, k = e % 81, kh = k / 9, kw = k % 9;
      uint32_t m0 = 0, m1 = 0;
      int oc0 = och * 2;
      #pragma unroll
      for (int ic = 0; ic < 32; ++ic) {
        if (w2[(oc0*32 + ic)*81 + k] < 0.f)     m0 |= 1u << ic;
        if (w2[((oc0+1)*32 + ic)*81 + k] < 0.f) m1 |= 1u << ic;
      }
      int idx = ((och*9 + kh)*10 + kw)*2;
      W2P[idx] = m0; W2P[idx+1] = m1;
    }
    if (bid == 0 && tid < 72) {  // zero pad words kw=9
      int idx = (tid*10 + 9)*2;
      W2P[idx] = 0; W2P[idx+1] = 0;
    }
  } else if (bid < 7) {       // w3: 648 items over 3 blocks (216 each)
    uint32_t* W3P = (uint32_t*)(ws + OFF_W3P);
    int e = (bid - 4) * 216 + tid;
    if (tid < 216) {
      int oc = e / 81, k = e % 81, kh = k / 9, kw = k % 9;
      uint32_t m = 0;
      #pragma unroll
      for (int ic = 0; ic < 16; ++ic)
        if (w3[(oc*16 + ic)*81 + k] < 0.f) m |= 1u << ic;
      W3P[(oc*9 + kh)*12 + kw] = m;
    }
    if (bid == 4 && tid < 216) { int row = tid / 3, p = tid % 3; W3P[row*12 + 9 + p] = 0; }
  } else if (bid == 7) {      // w1: 96 words, 27 loads each
    uint32_t* W1R3 = (uint32_t*)(ws + OFF_W1R3);
    if (tid < 96) {
      int oc = tid / 3, i = tid % 3;
      uint32_t m = 0;
      #pragma unroll
      for (int rr = 0; rr < 3; ++rr)
        #pragma unroll
        for (int kw = 0; kw < 9; ++kw)
          if (w1[oc*81 + (3*i+rr)*9 + kw] < 0.f) m |= 1u << (rr*9 + kw);
      W1R3[tid] = m;
    }
  } else if (bid == 8) {      // wl via coalesced ballot (64 consecutive floats = one uint64) + bl
    uint64_t* WLB = (uint64_t*)(ws + OFF_WLB);
    float* SBL = (float*)(ws + OFF_SBL);
    #pragma unroll
    for (int i = 0; i < 5; ++i) {
      int idx = i*256 + tid;              // 1280 floats total
      float v = wl[idx];
      unsigned long long m = __ballot(v < 0.f);
      if ((tid & 63) == 0) WLB[idx >> 6] = m;
    }
    if (tid < 10) SBL[tid] = (bl[tid] >= 0.f) ? 1.f : -1.f;
  }

  // ---- all blocks: layer-1 window sums for 8 images -> atomicAdd Ttot ----
  __shared__ uint32_t rowm[224];
  __shared__ int Tacc[81];
  if (tid < 81) Tacc[tid] = 0;
  __syncthreads();
  const int img0 = bid * 8;
  if (tid < 224) {
    int il = tid / 28, r = tid % 28;
    const float4* xr = (const float4*)(x + (size_t)(img0 + il) * 784 + r * 28);
    uint32_t m = 0;
    #pragma unroll
    for (int j = 0; j < 7; ++j) {
      float4 v = xr[j];
      if (v.x < 0.f) m |= 1u << (j*4+0);
      if (v.y < 0.f) m |= 1u << (j*4+1);
      if (v.z < 0.f) m |= 1u << (j*4+2);
      if (v.w < 0.f) m |= 1u << (j*4+3);
    }
    rowm[tid] = m;
  }
  __syncthreads();
  if (tid < 72) {             // (il, kw): sliding 20-row window of neg counts
    int il = tid / 9, kw = tid % 9;
    int base = il * 28;
    int n9[9];
    int sum20 = 0;
    #pragma unroll
    for (int r = 0; r < 20; ++r) {
      int n = __popc((rowm[base + r] >> kw) & 0xFFFFFu);
      if (r < 9) n9[r] = n;
      sum20 += n;
    }
    atomicAdd(&Tacc[kw], 400 - 2*sum20);
    #pragma unroll
    for (int kh = 1; kh <= 8; ++kh) {
      int nadd = __popc((rowm[base + kh + 19] >> kw) & 0xFFFFFu);
      sum20 += nadd - n9[kh-1];
      atomicAdd(&Tacc[kh*9 + kw], 400 - 2*sum20);
    }
  }
  __syncthreads();
  if (tid < 81) atomicAdd(&Ttot[tid], Tacc[tid]);
}

// ---------------------------------------------------------------- K2: conv1 (recompute) + conv2  [proven body, unchanged]
#define K2_IMGS 8
__global__ __launch_bounds__(256) void k2_conv12(const float* __restrict__ x,
                                                 uint8_t* __restrict__ ws) {
  const uint32_t* W1R3g = (const uint32_t*)(ws + OFF_W1R3);
  const uint32_t* W2Pg  = (const uint32_t*)(ws + OFF_W2P);
  const int* Ttot = (const int*)(ws + OFF_TTOT);
  int* S2P = (int*)(ws + OFF_S2P);

  __shared__ uint32_t __attribute__((aligned(16))) rowm[K2_IMGS*28];
  __shared__ uint32_t __attribute__((aligned(16))) w1r3[96];
  __shared__ uint32_t __attribute__((aligned(16))) w2p[1440];
  __shared__ int tlds[81];
  __shared__ int t1s[32];
  __shared__ uint32_t __attribute__((aligned(16))) A1s[K2_IMGS*400];
  __shared__ int s2acc[16];

  const int tid = threadIdx.x;
  const int img0 = blockIdx.x * K2_IMGS;

  for (int e = tid; e < 96; e += 256)   w1r3[e] = W1R3g[e];
  for (int e = tid; e < 1440; e += 256) w2p[e]  = W2Pg[e];
  if (tid < 81) tlds[tid] = Ttot[tid];
  if (tid < 16) s2acc[tid] = 0;
  if (tid < K2_IMGS*28) {
    int il = tid / 28, rr = tid % 28;
    const float4* xr = (const float4*)(x + (size_t)(img0 + il) * 784 + rr * 28);
    uint32_t m = 0;
    #pragma unroll
    for (int j = 0; j < 7; ++j) {
      float4 v = xr[j];
      if (v.x < 0.f) m |= 1u << (j*4+0);
      if (v.y < 0.f) m |= 1u << (j*4+1);
      if (v.z < 0.f) m |= 1u << (j*4+2);
      if (v.w < 0.f) m |= 1u << (j*4+3);
    }
    rowm[tid] = m;
  }
  __syncthreads();

  // layer-1 thresholds (odd parity): t1 = smallest odd integer >= S1/N1
  if (tid < 32) {
    long long S = 0;
    for (int kh = 0; kh < 9; ++kh)
      for (int kw = 0; kw < 9; ++kw) {
        int bit = (w1r3[tid*3 + kh/3] >> ((kh%3)*9 + kw)) & 1;
        S += (long long)(1 - 2*bit) * tlds[kh*9 + kw];
      }
    const long long N1 = (long long)BATCH * 400;
    long long q = S / N1, rr = S % N1;
    long long t = q + (rr > 0 ? 1 : 0);
    if ((t & 1) == 0) t += 1;
    t1s[tid] = (int)t;
  }
  __syncthreads();

  // conv1 + binarize -> A1s. Task = (il, oh, 5-ow group): 640 tasks.
  for (int G = tid; G < K2_IMGS*80; G += 256) {
    int il = G / 80, rem = G - il*80;
    int oh = rem >> 2, ow0 = (rem & 3) * 5;
    uint32_t R[9];
    #pragma unroll
    for (int i = 0; i < 9; ++i) R[i] = rowm[il*28 + oh + i];
    uint32_t win[5][3];
    #pragma unroll
    for (int j = 0; j < 5; ++j) {
      int ow = ow0 + j;
      #pragma unroll
      for (int i = 0; i < 3; ++i) {
        uint32_t b0 = (R[3*i]   >> ow) & 0x1FFu;
        uint32_t b1 = (R[3*i+1] >> ow) & 0x1FFu;
        uint32_t b2 = (R[3*i+2] >> ow) & 0x1FFu;
        win[j][i] = b0 | (b1 << 9) | (b2 << 18);
      }
    }
    uint32_t mask[5] = {0,0,0,0,0};
    #pragma unroll
    for (int ocg = 0; ocg < 4; ++ocg) {
      const uint4* wp = (const uint4*)&w1r3[ocg*24];
      uint32_t wr[24];
      #pragma unroll
      for (int q = 0; q < 6; ++q) {
        uint4 v = wp[q];
        wr[q*4+0]=v.x; wr[q*4+1]=v.y; wr[q*4+2]=v.z; wr[q*4+3]=v.w;
      }
      #pragma unroll
      for (int o8 = 0; o8 < 8; ++o8) {
        int oc = ocg*8 + o8;
        int t = t1s[oc];
        #pragma unroll
        for (int j = 0; j < 5; ++j) {
          int mm = __popc(win[j][0] ^ wr[o8*3])
                 + __popc(win[j][1] ^ wr[o8*3+1])
                 + __popc(win[j][2] ^ wr[o8*3+2]);
          mask[j] |= (uint32_t)((81 - 2*mm) < t) << oc;
        }
      }
    }
    #pragma unroll
    for (int j = 0; j < 5; ++j) A1s[il*400 + oh*20 + ow0 + j] = mask[j];
  }
  __syncthreads();

  // conv2: task = (il, oy, oc-pair): 768 tasks, 3 per thread.
  uint32_t* Z2w = (uint32_t*)(ws + OFF_Z2);
  const int och = tid & 7, oc0 = och << 1;
  int sl0 = 0, sl1 = 0;
  for (int r = 0; r < 3; ++r) {
    int G = tid + r*256;
    int il = G / 96, rem = G - il*96;
    int oy = rem >> 3;
    const uint32_t* A = &A1s[il*400 + oy*20];
    int acc0[12], acc1[12];
    #pragma unroll
    for (int p = 0; p < 12; ++p) { acc0[p] = 0; acc1[p] = 0; }
    for (int kh = 0; kh < 9; ++kh) {
      const uint4* ar = (const uint4*)(A + kh*20);
      uint32_t a[20];
      #pragma unroll
      for (int q = 0; q < 5; ++q) {
        uint4 v = ar[q];
        a[q*4+0]=v.x; a[q*4+1]=v.y; a[q*4+2]=v.z; a[q*4+3]=v.w;
      }
      const uint4* wp4 = (const uint4*)&w2p[(och*9 + kh)*20];
      uint32_t wbuf[20];
      #pragma unroll
      for (int q = 0; q < 5; ++q) {
        uint4 v = wp4[q];
        wbuf[q*4+0]=v.x; wbuf[q*4+1]=v.y; wbuf[q*4+2]=v.z; wbuf[q*4+3]=v.w;
      }
      #pragma unroll
      for (int kw = 0; kw < 9; ++kw) {
        uint32_t w0 = wbuf[2*kw], w1v = wbuf[2*kw+1];
        #pragma unroll
        for (int px = 0; px < 12; ++px) {
          acc0[px] += __popc(a[kw+px] ^ w0);
          acc1[px] += __popc(a[kw+px] ^ w1v);
        }
      }
    }
    size_t wbase = (size_t)(img0+il)*1152 + (size_t)oy*96 + och;
    #pragma unroll
    for (int px = 0; px < 12; ++px) {
      int z0 = 2592 - 2*acc0[px], z1v = 2592 - 2*acc1[px];
      sl0 += z0; sl1 += z1v;
      Z2w[wbase + px*8] = (uint32_t)(uint16_t)(int16_t)z0
                        | ((uint32_t)(uint16_t)(int16_t)z1v << 16);
    }
  }
  atomicAdd(&s2acc[oc0],   sl0);
  atomicAdd(&s2acc[oc0+1], sl1);
  __syncthreads();
  if (tid < 16) S2P[blockIdx.x*16 + tid] = s2acc[tid];
}

// ---------------------------------------------------------------- K3: t2-reduce + binarize + conv3  [R5 shape: grid 256, 32 imgs/block]
__global__ __launch_bounds__(256) void k3_conv3(uint8_t* __restrict__ ws) {
  const int* S2P = (const int*)(ws + OFF_S2P);
  const uint32_t* W3Pg = (const uint32_t*)(ws + OFF_W3P);
  const uint32_t* Z2w = (const uint32_t*)(ws + OFF_Z2);
  uint32_t* Z3w = (uint32_t*)(ws + OFF_Z3);
  int* S3P = (int*)(ws + OFF_S3P);

  __shared__ uint32_t __attribute__((aligned(16))) w3p[864];
  __shared__ int part[256];
  __shared__ int t2s[16];
  __shared__ uint32_t __attribute__((aligned(16))) A2[32*144];
  __shared__ int s3acc[8];

  const int tid = threadIdx.x;
  const int img0 = blockIdx.x * 32;

  // phase 0: redundant t2 reduction from S2P (64 KB, L2-resident)
  {
    int c = tid & 15, g = tid >> 4;
    int s = 0;
    for (int j = 0; j < 64; ++j) s += S2P[(g + 16*j)*16 + c];
    part[tid] = s;
  }
  for (int e = tid; e < 864; e += 256) w3p[e] = W3Pg[e];
  if (tid < 8) s3acc[tid] = 0;
  __syncthreads();
  if (tid < 16) {
    long long S = 0;
    #pragma unroll
    for (int g = 0; g < 16; ++g) S += (long long)part[g*16 + tid];
    const long long N2 = (long long)BATCH * 144;
    long long q = S / N2, r = S % N2;
    long long t = q + (r > 0 ? 1 : 0);
    if (t & 1) t += 1;   // z2 is even
    t2s[tid] = (int)t;
  }
  __syncthreads();

  // phase 1: binarize z2 -> A2 bit masks. 32 imgs x 144 px, coalesced 32B/px reads.
  #pragma unroll
  for (int j = 0; j < 18; ++j) {
    int idx = tid + j*256;           // 0..4607
    const uint4* zp = (const uint4*)&Z2w[(size_t)(img0 + idx/144)*1152 + (size_t)(idx%144)*8];
    uint4 v0 = zp[0], v1 = zp[1];
    uint32_t zz[8] = {v0.x,v0.y,v0.z,v0.w, v1.x,v1.y,v1.z,v1.w};
    uint32_t m = 0;
    #pragma unroll
    for (int i = 0; i < 8; ++i) {
      int zlo = (int)(short)(zz[i] & 0xFFFFu);
      int zhi = (int)zz[i] >> 16;
      m |= (uint32_t)(zlo < t2s[2*i])   << (2*i);
      m |= (uint32_t)(zhi < t2s[2*i+1]) << (2*i+1);
    }
    A2[idx] = m;
  }
  __syncthreads();

  // phase 2: conv3. Task = (il, oc) = 32*8 = 256, one per thread, 16 px each.
  const int il = tid >> 3, oc = tid & 7;
  int acc[16];
  #pragma unroll
  for (int i = 0; i < 16; ++i) acc[i] = 0;
  #pragma unroll
  for (int r = 0; r < 12; ++r) {
    const uint4* ar = (const uint4*)&A2[il*144 + r*12];
    uint4 v0 = ar[0], v1 = ar[1], v2 = ar[2];
    uint32_t a[12] = {v0.x,v0.y,v0.z,v0.w, v1.x,v1.y,v1.z,v1.w, v2.x,v2.y,v2.z,v2.w};
    #pragma unroll
    for (int oy = 0; oy < 4; ++oy) {
      if (r - oy >= 0 && r - oy <= 8) {
        int kh = r - oy;
        const uint4* wr = (const uint4*)&w3p[(oc*9 + kh)*12];
        uint4 w0 = wr[0], w1v = wr[1], w2v = wr[2];
        uint32_t w[9] = {w0.x,w0.y,w0.z,w0.w, w1v.x,w1v.y,w1v.z,w1v.w, w2v.x};
        #pragma unroll
        for (int ox = 0; ox < 4; ++ox) {
          int m = 0;
          #pragma unroll
          for (int kw = 0; kw < 9; ++kw) m += __popc(a[ox+kw] ^ w[kw]);
          acc[oy*4+ox] += m;
        }
      }
    }
  }
  // z3 = 1296 - 2*mism; store [img][oc][16 px] int16; sum for channel means
  int ssum = 0;
  uint32_t packed[8];
  #pragma unroll
  for (int h = 0; h < 8; ++h) {
    int za = 1296 - 2*acc[2*h], zb = 1296 - 2*acc[2*h+1];
    ssum += za + zb;
    packed[h] = (uint32_t)(uint16_t)(int16_t)za | ((uint32_t)(uint16_t)(int16_t)zb << 16);
  }
  uint4* zp = (uint4*)&Z3w[(size_t)(img0 + il)*64 + oc*8];
  zp[0] = make_uint4(packed[0], packed[1], packed[2], packed[3]);
  zp[1] = make_uint4(packed[4], packed[5], packed[6], packed[7]);
  atomicAdd(&s3acc[oc], ssum);
  __syncthreads();
  if (tid < 8) S3P[blockIdx.x*8 + tid] = s3acc[tid];
}

// ---------------------------------------------------------------- K4: t3-reduce + conv4 + bias -> out  [R5 shape: grid 32 x 256]
__global__ __launch_bounds__(256) void k4_final(uint8_t* __restrict__ ws,
                                                float* __restrict__ out) {
  const uint32_t* Z3w = (const uint32_t*)(ws + OFF_Z3);
  const int* S3P = (const int*)(ws + OFF_S3P);
  const uint64_t* WLBg = (const uint64_t*)(ws + OFF_WLB);
  const float* SBLg = (const float*)(ws + OFF_SBL);
  __shared__ int red[64];
  __shared__ int t3[8];
  __shared__ uint64_t wlb[20];
  __shared__ float sbl[10];
  const int tid = threadIdx.x;
  if (tid < 64) {
    int oc = tid & 7, g = tid >> 3;   // 8 groups over 256 partials
    int s = 0;
    for (int b = g; b < 256; b += 8) s += S3P[b*8 + oc];
    red[tid] = s;
  }
  if (tid >= 64 && tid < 84) wlb[tid - 64] = WLBg[tid - 64];
  if (tid >= 96 && tid < 106) sbl[tid - 96] = SBLg[tid - 96];
  __syncthreads();
  if (tid < 8) {
    long long S = 0;
    #pragma unroll
    for (int g = 0; g < 8; ++g) S += (long long)red[g*8 + tid];
    const long long N3 = (long long)BATCH * 16;
    long long q = S / N3, r = S % N3;
    long long t = q + (r > 0 ? 1 : 0);
    if (t & 1) t += 1;   // z3 is even
    t3[tid] = (int)t;
  }
  __syncthreads();
  int img = blockIdx.x * 256 + tid;
  const uint4* zp = (const uint4*)&Z3w[(size_t)img * 64];
  uint32_t zz[64];   // full 64 words = 8 oc x 16 px
  #pragma unroll
  for (int q = 0; q < 16; ++q) {
    uint4 v = zp[q];
    zz[q*4+0]=v.x; zz[q*4+1]=v.y; zz[q*4+2]=v.z; zz[q*4+3]=v.w;
  }
  uint64_t a0 = 0, a1 = 0;
  #pragma unroll
  for (int j = 0; j < 64; ++j) {
    int z = (j & 1) ? ((int)zz[j>>1] >> 16) : (int)(short)(zz[j>>1] & 0xFFFFu);
    a0 |= (uint64_t)(z < t3[j >> 4]) << j;
  }
  #pragma unroll
  for (int j = 0; j < 64; ++j) {
    int z = (j & 1) ? ((int)zz[32 + (j>>1)] >> 16) : (int)(short)(zz[32 + (j>>1)] & 0xFFFFu);
    a1 |= (uint64_t)(z < t3[(64 + j) >> 4]) << j;
  }
  #pragma unroll
  for (int oc = 0; oc < 10; ++oc) {
    int mism = __popcll(a0 ^ wlb[oc*2]) + __popcll(a1 ^ wlb[oc*2 + 1]);
    out[(size_t)img*10 + oc] = (float)(128 - 2*mism) + sbl[oc];
  }
}

// ----------------------------------------------------------------
extern "C" void kernel_launch(void* const* d_in, const int* in_sizes, int n_in,
                              void* d_out, int out_size, void* d_ws, size_t ws_size,
                              hipStream_t stream) {
  (void)in_sizes; (void)n_in; (void)out_size; (void)ws_size;
  const float* x  = (const float*)d_in[0];
  const float* w1 = (const float*)d_in[1];
  // d_in[2]=b1, d_in[4]=b2, d_in[6]=b3: biases cancel under BN -> unused
  const float* w2 = (const float*)d_in[3];
  const float* w3 = (const float*)d_in[5];
  const float* wl = (const float*)d_in[7];
  const float* bl = (const float*)d_in[8];
  uint8_t* ws = (uint8_t*)d_ws;
  float* out = (float*)d_out;

  // zero Ttot accumulator (ws is poisoned 0xAA each call); S2P/S3P are fully overwritten
  hipMemsetAsync(ws + OFF_TTOT, 0, 324, stream);
  k1_pack_tsum<<<1024, 256, 0, stream>>>(x, w1, w2, w3, wl, bl, ws);
  k2_conv12<<<1024, 256, 0, stream>>>(x, ws);
  k3_conv3<<<256, 256, 0, stream>>>(ws);
  k4_final<<<32, 256, 0, stream>>>(ws, out);
}